// Round 2
// baseline (1001.139 us; speedup 1.0000x reference)
//
#include <hip/hip_runtime.h>
#include <stdint.h>
#include <stddef.h>

typedef unsigned short bf16u;
typedef __attribute__((ext_vector_type(8))) short short8;
typedef __attribute__((ext_vector_type(4))) float f32x4;

__device__ __forceinline__ bf16u f2bf(float f) {
  union { float f; unsigned u; } v; v.f = f;
  unsigned r = v.u + 0x7FFFu + ((v.u >> 16) & 1u);
  return (bf16u)(r >> 16);
}

#define GL16(g, l) __builtin_amdgcn_global_load_lds( \
    (const __attribute__((address_space(1))) unsigned int*)(g), \
    (__attribute__((address_space(3))) unsigned int*)(l), 16, 0, 0)

// ---------------- GEMM: C = A[M,K] @ BT[N,K]^T + bias, fused epilogues ----
enum { EPI_BF16 = 0, EPI_BF16_RELU = 1, EPI_VT = 2, EPI_RES = 3, EPI_GATE = 4 };

template<int EPI>
__global__ __launch_bounds__(256, 2) void gemm_k(
    const bf16u* __restrict__ A, const bf16u* __restrict__ BT,
    const float* __restrict__ bias, const float* __restrict__ res,
    const float* __restrict__ gates,
    bf16u* __restrict__ outb, float* __restrict__ outf,
    int M, int N, int K, int slog, int egate, int firste)
{
  __shared__ bf16u Ab[2][128 * 32];
  __shared__ bf16u Bb[2][128 * 32];
  const int tid = threadIdx.x, lane = tid & 63, w = tid >> 6;
  const int wm = w >> 1, wn = w & 1;
  const int nbt = N >> 7;
  const int mt = blockIdx.x / nbt, nt = blockIdx.x - mt * nbt;
  const int bm = mt << 7, bn = nt << 7;

  const int srow = lane >> 2;            // 0..15
  const int scol = (lane & 3) << 3;      // 0,8,16,24
  const bf16u* ap0 = A + (size_t)(bm + w * 16 + srow) * K + scol;
  const bf16u* ap1 = ap0 + (size_t)64 * K;
  const bf16u* bp0 = BT + (size_t)(bn + w * 16 + srow) * K + scol;
  const bf16u* bp1 = bp0 + (size_t)64 * K;

  f32x4 acc[4][4] = {};
  const int NT = K >> 5;

  GL16(ap0, &Ab[0][w * 512]);
  GL16(ap1, &Ab[0][(4 + w) * 512]);
  GL16(bp0, &Bb[0][w * 512]);
  GL16(bp1, &Bb[0][(4 + w) * 512]);
  __syncthreads();

  const int rl = lane & 15, kg = (lane >> 4) << 3;
  int cur = 0;
  for (int kt = 0; kt < NT; ++kt) {
    if (kt + 1 < NT) {
      const int ko = (kt + 1) << 5;
      const int nb = cur ^ 1;
      GL16(ap0 + ko, &Ab[nb][w * 512]);
      GL16(ap1 + ko, &Ab[nb][(4 + w) * 512]);
      GL16(bp0 + ko, &Bb[nb][w * 512]);
      GL16(bp1 + ko, &Bb[nb][(4 + w) * 512]);
    }
    short8 af[4], bfv[4];
    #pragma unroll
    for (int i = 0; i < 4; ++i)
      af[i] = *(const short8*)&Ab[cur][(wm * 64 + i * 16 + rl) * 32 + kg];
    #pragma unroll
    for (int j = 0; j < 4; ++j)
      bfv[j] = *(const short8*)&Bb[cur][(wn * 64 + j * 16 + rl) * 32 + kg];
    #pragma unroll
    for (int i = 0; i < 4; ++i)
      #pragma unroll
      for (int j = 0; j < 4; ++j)
        acc[i][j] = __builtin_amdgcn_mfma_f32_16x16x32_bf16(af[i], bfv[j], acc[i][j], 0, 0, 0);
    __syncthreads();
    cur ^= 1;
  }

  const int r0 = bm + wm * 64, c0 = bn + wn * 64;
  const int rsub = (lane >> 4) << 2;
  #pragma unroll
  for (int j = 0; j < 4; ++j) {
    const int col = c0 + j * 16 + rl;
    const float bs = bias ? bias[col] : 0.f;
    #pragma unroll
    for (int i = 0; i < 4; ++i) {
      const f32x4 v = acc[i][j];
      #pragma unroll
      for (int jj = 0; jj < 4; ++jj) {
        const int row = r0 + i * 16 + rsub + jj;
        float val = v[jj] + bs;
        if (EPI == EPI_BF16) {
          outb[(size_t)row * N + col] = f2bf(val);
        } else if (EPI == EPI_BF16_RELU) {
          outb[(size_t)row * N + col] = f2bf(val > 0.f ? val : 0.f);
        } else if (EPI == EPI_VT) {
          const int b_ = row >> slog, t_ = row & ((1 << slog) - 1);
          outb[(((size_t)(b_ * 8 + (col >> 6)) << 6) + (size_t)(col & 63)) * ((size_t)1 << slog) + t_] = f2bf(val);
        } else if (EPI == EPI_RES) {
          outf[(size_t)row * N + col] = res[(size_t)row * N + col] + val;
        } else { // EPI_GATE
          const float g = gates[(size_t)row * 4 + egate];
          const size_t oi = (size_t)row * N + col;
          const float c = g * val;
          outf[oi] = firste ? c : (outf[oi] + c);
        }
      }
    }
  }
}

// ---------------- Flash attention (64-row Q tiles, swapped mfma(K,Q)) -----
template<bool CAUSAL>
__global__ __launch_bounds__(256, 2) void attn_k(
    const bf16u* __restrict__ Q, const bf16u* __restrict__ Kg,
    const bf16u* __restrict__ VT, bf16u* __restrict__ O,
    int Sq, int Sk)
{
  __shared__ bf16u Kl[64 * 64];
  __shared__ bf16u Vl[64 * 64];
  __shared__ bf16u Pl[64 * 64];
  const int nqt = Sq >> 6;
  const int bh = blockIdx.x / nqt, qt = blockIdx.x - bh * nqt;
  const int b = bh >> 3, h = bh & 7;
  const int tid = threadIdx.x, lane = tid & 63, w = tid >> 6;
  const int rl = lane & 15, g4 = lane >> 4;

  const int qrow = qt * 64 + w * 16 + rl;
  const bf16u* qp = Q + (size_t)(b * Sq + qrow) * 512 + h * 64 + g4 * 8;
  const short8 qf0 = *(const short8*)qp;
  const short8 qf1 = *(const short8*)(qp + 32);

  f32x4 oacc[4] = {};
  float ml = -1e30f, ll = 0.f;
  const int KT = CAUSAL ? (qt + 1) : (Sk >> 6);

  // staging: 4 threads per row, each thread stages TWO 16B chunks (full 128B row)
  const int str = tid >> 2, stc = tid & 3;
  const int sw_st = (str & 7) << 4;
  const bf16u* kq = Kg + (size_t)(b * Sk + str) * 512 + h * 64 + stc * 8;
  const bf16u* vq = VT + (size_t)(bh * 64 + str) * Sk + stc * 8;
  char* const klw0 = (char*)Kl + str * 128 + ((stc * 16) ^ sw_st);
  char* const klw1 = (char*)Kl + str * 128 + ((stc * 16 + 64) ^ sw_st);
  char* const vlw0 = (char*)Vl + str * 128 + ((stc * 16) ^ sw_st);
  char* const vlw1 = (char*)Vl + str * 128 + ((stc * 16 + 64) ^ sw_st);

  const int qr = w * 16 + rl;
  char* const pbase = (char*)Pl + qr * 128;
  const int swq = (qr & 7) << 4;

  for (int kt = 0; kt < KT; ++kt) {
    __syncthreads();
    {
      const bf16u* ks = kq + (size_t)kt * 64 * 512;
      const bf16u* vs = vq + kt * 64;
      *(short8*)klw0 = *(const short8*)ks;
      *(short8*)klw1 = *(const short8*)(ks + 32);
      *(short8*)vlw0 = *(const short8*)vs;
      *(short8*)vlw1 = *(const short8*)(vs + 32);
    }
    __syncthreads();

    // S^T tile: rows = k index, cols = q (per-lane q = rl)
    f32x4 st[4] = {};
    #pragma unroll
    for (int mi = 0; mi < 4; ++mi) {
      const int kr = mi * 16 + rl;
      const char* kb_ = (const char*)Kl + kr * 128;
      const int sw = (kr & 7) << 4;
      const short8 kf0 = *(const short8*)(kb_ + ((g4 * 16) ^ sw));
      const short8 kf1 = *(const short8*)(kb_ + ((g4 * 16 + 64) ^ sw));
      st[mi] = __builtin_amdgcn_mfma_f32_16x16x32_bf16(kf0, qf0, st[mi], 0, 0, 0);
      st[mi] = __builtin_amdgcn_mfma_f32_16x16x32_bf16(kf1, qf1, st[mi], 0, 0, 0);
    }

    const int qg = qt * 64 + qr;
    float sv[16];
    float pm = -1e30f;
    #pragma unroll
    for (int mi = 0; mi < 4; ++mi) {
      #pragma unroll
      for (int jj = 0; jj < 4; ++jj) {
        float s = st[mi][jj] * 0.125f;
        if (CAUSAL) {
          const int kgi = kt * 64 + mi * 16 + g4 * 4 + jj;
          if (kgi > qg) s = -1e30f;
        }
        sv[mi * 4 + jj] = s;
        pm = fmaxf(pm, s);
      }
    }
    pm = fmaxf(pm, __shfl_xor(pm, 16));
    pm = fmaxf(pm, __shfl_xor(pm, 32));
    const float mnew = fmaxf(ml, pm);
    const float alpha = exp2f((ml - mnew) * 1.44269504f);
    float ps = 0.f;
    bf16u pb[16];
    #pragma unroll
    for (int ii = 0; ii < 16; ++ii) {
      const float p = exp2f((sv[ii] - mnew) * 1.44269504f);
      ps += p;
      pb[ii] = f2bf(p);
    }
    ps += __shfl_xor(ps, 16);
    ps += __shfl_xor(ps, 32);
    ll = ll * alpha + ps;
    ml = mnew;

    #pragma unroll
    for (int jj = 0; jj < 4; ++jj) {
      const float aj = __shfl(alpha, g4 * 4 + jj);
      #pragma unroll
      for (int ni = 0; ni < 4; ++ni) oacc[ni][jj] *= aj;
    }

    // write P (bf16) to LDS in [q][k] layout (swizzled), own rows only
    #pragma unroll
    for (int mi = 0; mi < 4; ++mi) {
      #pragma unroll
      for (int jp = 0; jp < 2; ++jp) {
        const unsigned pk = (unsigned)pb[mi * 4 + jp * 2] | ((unsigned)pb[mi * 4 + jp * 2 + 1] << 16);
        const int kx2 = mi * 32 + g4 * 8 + jp * 4;
        *(unsigned*)(pbase + (kx2 ^ swq)) = pk;
      }
    }
    asm volatile("s_waitcnt lgkmcnt(0)" ::: "memory");
    // PV
    #pragma unroll
    for (int ks = 0; ks < 2; ++ks) {
      const short8 pf = *(const short8*)(pbase + ((g4 * 16 + ks * 64) ^ swq));
      #pragma unroll
      for (int ni = 0; ni < 4; ++ni) {
        const int vr = ni * 16 + rl;
        const short8 vf = *(const short8*)((const char*)Vl + vr * 128 + ((g4 * 16 + ks * 64) ^ ((vr & 7) << 4)));
        oacc[ni] = __builtin_amdgcn_mfma_f32_16x16x32_bf16(pf, vf, oacc[ni], 0, 0, 0);
      }
    }
  }

  #pragma unroll
  for (int jj = 0; jj < 4; ++jj) {
    const float lj = __shfl(ll, g4 * 4 + jj);
    const float inv = 1.f / lj;
    const int row = qt * 64 + w * 16 + g4 * 4 + jj;
    #pragma unroll
    for (int ni = 0; ni < 4; ++ni)
      O[(size_t)(b * Sq + row) * 512 + h * 64 + ni * 16 + rl] = f2bf(oacc[ni][jj] * inv);
  }
}

// ---------------- LayerNorm (wave per row, D=512), optional add / bf16 out
template<bool ADD, bool BOUT>
__global__ __launch_bounds__(256, 4) void ln_k(
    const float* __restrict__ X, const float* __restrict__ Y,
    const float* __restrict__ gam, const float* __restrict__ bet,
    float* __restrict__ outf, bf16u* __restrict__ outb)
{
  const int row = blockIdx.x * 4 + (threadIdx.x >> 6);
  const int lane = threadIdx.x & 63;
  const float* xp = X + (size_t)row * 512 + lane * 8;
  float v[8];
  {
    const float4 t0 = *(const float4*)xp;
    const float4 t1 = *(const float4*)(xp + 4);
    v[0] = t0.x; v[1] = t0.y; v[2] = t0.z; v[3] = t0.w;
    v[4] = t1.x; v[5] = t1.y; v[6] = t1.z; v[7] = t1.w;
  }
  if (ADD) {
    const float* yp = Y + (size_t)row * 512 + lane * 8;
    const float4 t0 = *(const float4*)yp;
    const float4 t1 = *(const float4*)(yp + 4);
    v[0] += t0.x; v[1] += t0.y; v[2] += t0.z; v[3] += t0.w;
    v[4] += t1.x; v[5] += t1.y; v[6] += t1.z; v[7] += t1.w;
  }
  float s = 0.f, q = 0.f;
  #pragma unroll
  for (int i = 0; i < 8; ++i) { s += v[i]; q += v[i] * v[i]; }
  #pragma unroll
  for (int off = 1; off < 64; off <<= 1) {
    s += __shfl_xor(s, off);
    q += __shfl_xor(q, off);
  }
  const float mean = s * (1.f / 512.f);
  const float var = q * (1.f / 512.f) - mean * mean;
  const float rs = rsqrtf(var + 1e-5f);
  float gv[8], bv[8];
  {
    const float4 t0 = *(const float4*)(gam + lane * 8);
    const float4 t1 = *(const float4*)(gam + lane * 8 + 4);
    gv[0] = t0.x; gv[1] = t0.y; gv[2] = t0.z; gv[3] = t0.w;
    gv[4] = t1.x; gv[5] = t1.y; gv[6] = t1.z; gv[7] = t1.w;
    const float4 u0 = *(const float4*)(bet + lane * 8);
    const float4 u1 = *(const float4*)(bet + lane * 8 + 4);
    bv[0] = u0.x; bv[1] = u0.y; bv[2] = u0.z; bv[3] = u0.w;
    bv[4] = u1.x; bv[5] = u1.y; bv[6] = u1.z; bv[7] = u1.w;
  }
  float o[8];
  #pragma unroll
  for (int i = 0; i < 8; ++i) o[i] = (v[i] - mean) * rs * gv[i] + bv[i];
  float* op = outf + (size_t)row * 512 + lane * 8;
  *(float4*)op = make_float4(o[0], o[1], o[2], o[3]);
  *(float4*)(op + 4) = make_float4(o[4], o[5], o[6], o[7]);
  if (BOUT) {
    union { bf16u u[8]; short8 v8; } pk;
    #pragma unroll
    for (int i = 0; i < 8; ++i) pk.u[i] = f2bf(o[i]);
    *(short8*)(outb + (size_t)row * 512 + lane * 8) = pk.v8;
  }
}

// ---------------- Gating: softmax(x@gw+gb), importance accumulation ------
__global__ __launch_bounds__(256, 4) void gate_k(
    const float* __restrict__ X, const float* __restrict__ gw,
    const float* __restrict__ gb, float* __restrict__ gates,
    float* __restrict__ imp)
{
  __shared__ float sh[4];
  const int tid = threadIdx.x;
  if (tid < 4) sh[tid] = 0.f;
  __syncthreads();
  const int row = blockIdx.x * 4 + (tid >> 6);
  const int lane = tid & 63;
  const float* xr = X + (size_t)row * 512;
  float a0 = 0.f, a1 = 0.f, a2 = 0.f, a3 = 0.f;
  for (int d = lane; d < 512; d += 64) {
    const float xv = xr[d];
    const float4 wv = *(const float4*)(gw + d * 4);
    a0 += xv * wv.x; a1 += xv * wv.y; a2 += xv * wv.z; a3 += xv * wv.w;
  }
  #pragma unroll
  for (int off = 1; off < 64; off <<= 1) {
    a0 += __shfl_xor(a0, off); a1 += __shfl_xor(a1, off);
    a2 += __shfl_xor(a2, off); a3 += __shfl_xor(a3, off);
  }
  if (lane == 0) {
    a0 += gb[0]; a1 += gb[1]; a2 += gb[2]; a3 += gb[3];
    const float m = fmaxf(fmaxf(a0, a1), fmaxf(a2, a3));
    const float e0 = exp2f((a0 - m) * 1.44269504f);
    const float e1 = exp2f((a1 - m) * 1.44269504f);
    const float e2 = exp2f((a2 - m) * 1.44269504f);
    const float e3 = exp2f((a3 - m) * 1.44269504f);
    const float inv = 1.f / (e0 + e1 + e2 + e3);
    float* gr = gates + (size_t)row * 4;
    const float g0 = e0 * inv, g1 = e1 * inv, g2 = e2 * inv, g3 = e3 * inv;
    gr[0] = g0; gr[1] = g1; gr[2] = g2; gr[3] = g3;
    atomicAdd(&sh[0], g0); atomicAdd(&sh[1], g1);
    atomicAdd(&sh[2], g2); atomicAdd(&sh[3], g3);
  }
  __syncthreads();
  if (tid < 4) atomicAdd(&imp[tid], sh[tid]);
}

__global__ void aux_k(const float* __restrict__ imp, float* __restrict__ out) {
  if (threadIdx.x == 0 && blockIdx.x == 0) {
    float s = 0.f;
    #pragma unroll
    for (int e = 0; e < 4; ++e) { const float v = imp[e] * (1.f / 16384.f); s += v * v; }
    out[0] = 4.f * s;
  }
}

// ---------------- fp32 -> bf16 convert, fp32 -> bf16 transpose -----------
__global__ __launch_bounds__(256, 4) void conv_k(const float* __restrict__ in, bf16u* __restrict__ out) {
  const size_t i = ((size_t)blockIdx.x * 256 + threadIdx.x) * 8;
  const float4 a = *(const float4*)(in + i);
  const float4 b = *(const float4*)(in + i + 4);
  union { bf16u u[8]; short8 v; } pk;
  pk.u[0] = f2bf(a.x); pk.u[1] = f2bf(a.y); pk.u[2] = f2bf(a.z); pk.u[3] = f2bf(a.w);
  pk.u[4] = f2bf(b.x); pk.u[5] = f2bf(b.y); pk.u[6] = f2bf(b.z); pk.u[7] = f2bf(b.w);
  *(short8*)(out + i) = pk.v;
}

__global__ __launch_bounds__(256, 4) void trans_k(
    const float* __restrict__ W, bf16u* __restrict__ WT, int K, int N)
{
  __shared__ float t[32][33];
  const int tx = threadIdx.x & 31, ty = threadIdx.x >> 5;
  const int n0 = blockIdx.x * 32, k0 = blockIdx.y * 32;
  #pragma unroll
  for (int i = 0; i < 4; ++i)
    t[ty + i * 8][tx] = W[(size_t)(k0 + ty + i * 8) * N + n0 + tx];
  __syncthreads();
  #pragma unroll
  for (int i = 0; i < 4; ++i)
    WT[(size_t)(n0 + ty + i * 8) * K + k0 + tx] = f2bf(t[tx][ty + i * 8]);
}

// ---------------- host orchestration -------------------------------------
extern "C" void kernel_launch(void* const* d_in, const int* in_sizes, int n_in,
                              void* d_out, int out_size, void* d_ws, size_t ws_size,
                              hipStream_t stream)
{
  const int B = 16, S = 1024, T = 512, D = 512, DF = 2048, E = 4;
  const int M = B * S;      // 16384
  const int Mc = B * T;     // 8192
  (void)in_sizes; (void)n_in; (void)out_size; (void)ws_size;

  const float* x      = (const float*)d_in[0];
  const float* cross  = (const float*)d_in[1];
  const float* gate_w = (const float*)d_in[18];
  const float* gate_b = (const float*)d_in[19];
  const float* exp_w1 = (const float*)d_in[20];
  const float* exp_b1 = (const float*)d_in[21];
  const float* exp_w2 = (const float*)d_in[22];
  const float* exp_b2 = (const float*)d_in[23];

  char* p = (char*)d_ws;
  auto alloc = [&](size_t bytes) -> char* {
    char* r = p;
    p += (bytes + 255) & ~(size_t)255;
    return r;
  };
  bf16u* xb    = (bf16u*)alloc((size_t)M * D * 2);
  bf16u* crb   = (bf16u*)alloc((size_t)Mc * D * 2);
  bf16u* wT    = (bf16u*)alloc((size_t)8 * D * D * 2);
  bf16u* w1T   = (bf16u*)alloc((size_t)E * DF * D * 2);
  bf16u* w2T   = (bf16u*)alloc((size_t)E * D * DF * 2);
  bf16u* qb    = (bf16u*)alloc((size_t)M * D * 2);
  bf16u* kb    = (bf16u*)alloc((size_t)M * D * 2);
  bf16u* vTb   = (bf16u*)alloc((size_t)M * D * 2);
  bf16u* ao    = (bf16u*)alloc((size_t)M * D * 2);
  float* xf    = (float*)alloc((size_t)M * D * 4);   // x1 -> x2 -> x3 -> x4 (in-place)
  bf16u* x2b   = (bf16u*)alloc((size_t)M * D * 2);   // bf16 copy of current LN output
  float* gates = (float*)alloc((size_t)M * 4 * 4);
  float* imp   = (float*)alloc(256);
  bf16u* hbuf  = (bf16u*)alloc((size_t)M * DF * 2);
  float* y     = (float*)alloc((size_t)M * D * 4);

  hipMemsetAsync(imp, 0, 32, stream);
  conv_k<<<(M * D) / 2048, 256, 0, stream>>>(x, xb);
  conv_k<<<(Mc * D) / 2048, 256, 0, stream>>>(cross, crb);
  for (int i = 0; i < 8; ++i)
    trans_k<<<dim3(D / 32, D / 32), 256, 0, stream>>>((const float*)d_in[2 + 2 * i], wT + (size_t)i * D * D, D, D);
  for (int e = 0; e < E; ++e)
    trans_k<<<dim3(DF / 32, D / 32), 256, 0, stream>>>(exp_w1 + (size_t)e * D * DF, w1T + (size_t)e * DF * D, D, DF);
  for (int e = 0; e < E; ++e)
    trans_k<<<dim3(D / 32, DF / 32), 256, 0, stream>>>(exp_w2 + (size_t)e * DF * D, w2T + (size_t)e * D * DF, DF, D);

  const int gMD  = (M / 128) * (D / 128);    // 512
  const int gMcD = (Mc / 128) * (D / 128);   // 256
  const int gMDF = (M / 128) * (DF / 128);   // 2048

  // ---- self-attention ----
  gemm_k<EPI_BF16><<<gMD, 256, 0, stream>>>(xb, wT + 0 * (size_t)D * D, (const float*)d_in[3], nullptr, nullptr, qb, nullptr, M, D, D, 0, 0, 0);
  gemm_k<EPI_BF16><<<gMD, 256, 0, stream>>>(xb, wT + 1 * (size_t)D * D, (const float*)d_in[5], nullptr, nullptr, kb, nullptr, M, D, D, 0, 0, 0);
  gemm_k<EPI_VT><<<gMD, 256, 0, stream>>>(xb, wT + 2 * (size_t)D * D, (const float*)d_in[7], nullptr, nullptr, vTb, nullptr, M, D, D, 10, 0, 0);
  attn_k<true><<<B * 8 * (S / 64), 256, 0, stream>>>(qb, kb, vTb, ao, S, S);
  gemm_k<EPI_RES><<<gMD, 256, 0, stream>>>(ao, wT + 3 * (size_t)D * D, (const float*)d_in[9], x, nullptr, nullptr, xf, M, D, D, 0, 0, 0);
  ln_k<false, true><<<M / 4, 256, 0, stream>>>(xf, nullptr, (const float*)d_in[24], (const float*)d_in[25], xf, x2b);

  // ---- cross-attention ----
  gemm_k<EPI_BF16><<<gMD, 256, 0, stream>>>(x2b, wT + 4 * (size_t)D * D, (const float*)d_in[11], nullptr, nullptr, qb, nullptr, M, D, D, 0, 0, 0);
  gemm_k<EPI_BF16><<<gMcD, 256, 0, stream>>>(crb, wT + 5 * (size_t)D * D, (const float*)d_in[13], nullptr, nullptr, kb, nullptr, Mc, D, D, 0, 0, 0);
  gemm_k<EPI_VT><<<gMcD, 256, 0, stream>>>(crb, wT + 6 * (size_t)D * D, (const float*)d_in[15], nullptr, nullptr, vTb, nullptr, Mc, D, D, 9, 0, 0);
  attn_k<false><<<B * 8 * (S / 64), 256, 0, stream>>>(qb, kb, vTb, ao, S, T);
  gemm_k<EPI_RES><<<gMD, 256, 0, stream>>>(ao, wT + 7 * (size_t)D * D, (const float*)d_in[17], xf, nullptr, nullptr, xf, M, D, D, 0, 0, 0);
  ln_k<false, true><<<M / 4, 256, 0, stream>>>(xf, nullptr, (const float*)d_in[26], (const float*)d_in[27], xf, x2b);

  // ---- MoE ----
  gate_k<<<M / 4, 256, 0, stream>>>(xf, gate_w, gate_b, gates, imp);
  aux_k<<<1, 64, 0, stream>>>(imp, (float*)d_out + (size_t)M * D);
  for (int e = 0; e < E; ++e) {
    gemm_k<EPI_BF16_RELU><<<gMDF, 256, 0, stream>>>(x2b, w1T + (size_t)e * DF * D, exp_b1 + (size_t)e * DF, nullptr, nullptr, hbuf, nullptr, M, DF, D, 0, 0, 0);
    gemm_k<EPI_GATE><<<gMD, 256, 0, stream>>>(hbuf, w2T + (size_t)e * D * DF, exp_b2 + (size_t)e * D, nullptr, gates, nullptr, y, M, D, DF, 0, e, e == 0 ? 1 : 0);
  }
  ln_k<true, false><<<M / 4, 256, 0, stream>>>(xf, y, (const float*)d_in[28], (const float*)d_in[29], (float*)d_out, nullptr);
}